// Round 13
// baseline (121.116 us; speedup 1.0000x reference)
//
#include <hip/hip_runtime.h>
#include <stdint.h>

// Problem constants (from reference): B=4, T=512, S=256, V=50257.
#define DIM_B 4
#define DIM_T 512
#define DIM_S 256
#define DIM_V 50257
#define NCHUNK 25731584u   // B*T*V/4 — exact (out_size % 4 == 0)
#define NZBLK  100514u     // NCHUNK/256 — exact, so no bounds check needed
#define HSZ   512          // per-row LDS hash slots (<=256 entries -> load 0.5)
#define HMSK  (HSZ - 1)

// ---- Zero kernel: proven giant-grid geometry (R12: ~57us, ~7.2 TB/s) ----
// One float4 store per short-lived thread; grid exactly tiles the buffer.
__global__ __launch_bounds__(256) void zero_clone_kernel(float4* __restrict__ out4) {
    const uint32_t g = blockIdx.x * 256u + threadIdx.x;
    out4[g] = make_float4(0.0f, 0.0f, 0.0f, 0.0f);
}

// ---- Patch kernel v3: full-128B-line composed stores (no write-allocate RMW) ----
// One block per row (b,t):
//  1. LDS hash v -> sum(p) (open addressing; exact duplicate accumulation).
//  2. Scan occupied slots: entries whose 32-float (128B) line lies FULLY inside
//     this row -> push line to LDS list (dups benign: idempotent stores);
//     boundary-line entries (<=2 lines/row) -> plain deduped 4B store.
//  3. Each listed line composed by 8 threads x float4 = contiguous 128B-aligned
//     full-line write -> skips the write-allocate fetch (R5's patch paid
//     ~124MB hidden RMW on 64/128B partial lines; R6 proved 64B is NOT enough
//     -> L2 line is 128B).
__global__ __launch_bounds__(256) void patch_kernel(
    const float* __restrict__ p_pos,   // [B, T, S]
    const int*   __restrict__ src,     // [B, S]  (int64 narrowed to int32)
    float*       __restrict__ out)     // [B, T, V]
{
    __shared__ int   hk[HSZ];
    __shared__ float hv[HSZ];
    __shared__ int   llist[256];       // <=1 push per occupied slot
    __shared__ int   lcount;

    const int row = blockIdx.x;        // row = b*T + t
    const int b   = row >> 9;          // T = 512
    const int tid = threadIdx.x;       // s index (S == blockDim.x == 256)

    for (int i = tid; i < HSZ; i += 256) { hk[i] = -1; hv[i] = 0.0f; }
    if (tid == 0) lcount = 0;
    __syncthreads();

    // ---- 1. hash build ----
    {
        const int   v = src[b * DIM_S + tid];
        const float p = p_pos[(size_t)row * DIM_S + tid];
        int h = v & HMSK;
        while (true) {
            const int prev = atomicCAS(&hk[h], -1, v);
            if (prev == -1 || prev == v) { atomicAdd(&hv[h], p); break; }
            h = (h + 1) & HMSK;
        }
    }
    __syncthreads();

    const long long rb = (long long)row * DIM_V;          // row base elem idx
    // 32-float (128B) lines fully contained in [rb, rb+V)
    const long long l_start = (rb + 31) >> 5;
    const long long l_end   = ((rb + DIM_V) >> 5) - 1;

    // ---- 2. slot scan: push contained lines / 4B-store boundary entries ----
    for (int i = tid; i < HSZ; i += 256) {
        const int v = hk[i];
        if (v >= 0) {
            const long long e    = rb + v;
            const long long line = e >> 5;
            if (line >= l_start && line <= l_end) {
                const int idx = atomicAdd(&lcount, 1);
                llist[idx] = (int)(line - l_start);
            } else {
                out[e] = hv[i];        // boundary line: plain 4B store (unique addr)
            }
        }
    }
    __syncthreads();

    // ---- 3. compose full 128B lines: 8 threads x float4 per line ----
    const int nitems = lcount << 3;    // 8 octets per line
    for (int it = tid; it < nitems; it += 256) {
        const long long line = l_start + (long long)llist[it >> 3];
        const int       q    = it & 7;                     // octet in line
        const long long e0   = (line << 5) + (q << 2);     // first elem of octet
        float4 o;
        float* po = (float*)&o;
        #pragma unroll
        for (int j = 0; j < 4; ++j) {
            const int col = (int)(e0 + j - rb);            // in [0, V)
            int   h   = col & HMSK;
            float val = 0.0f;
            while (true) {
                const int k = hk[h];
                if (k == col) { val = hv[h]; break; }
                if (k == -1)  break;
                h = (h + 1) & HMSK;
            }
            po[j] = val;
        }
        *(float4*)(out + e0) = o;      // 8 contiguous lanes -> full 128B line
    }
}

extern "C" void kernel_launch(void* const* d_in, const int* in_sizes, int n_in,
                              void* d_out, int out_size, void* d_ws, size_t ws_size,
                              hipStream_t stream) {
    const float* p_pos = (const float*)d_in[0];   // [B,T,S]
    // d_in[1] = p_target_vocab — dead data (shape-only in the reference).
    const int*   src   = (const int*)d_in[2];     // [B,S]
    float*       out   = (float*)d_out;           // [B,T,V]

    // Giant-grid zero (proven ~7.2 TB/s), then full-line composed patches.
    zero_clone_kernel<<<NZBLK, 256, 0, stream>>>((float4*)out);
    patch_kernel<<<DIM_B * DIM_T, DIM_S, 0, stream>>>(p_pos, src, out);
}